// Round 7
// baseline (202.978 us; speedup 1.0000x reference)
//
#include <hip/hip_runtime.h>
#include <hip/hip_bf16.h>
#include <stdint.h>

#define DIM 1024
#define SEQ 2048
#define NB 4
#define HEADS 8
#define HD 128
#define ROWS (NB*SEQ)   // 8192

typedef __attribute__((ext_vector_type(8))) short bf16x8;
typedef __attribute__((ext_vector_type(4))) float f32x4;

#define VMCNT(n) asm volatile("s_waitcnt vmcnt(" #n ")" ::: "memory")
#define SBAR()   __builtin_amdgcn_s_barrier()
#define SCHED0() __builtin_amdgcn_sched_barrier(0)

static __device__ __forceinline__ unsigned short f2bf(float f){
  union { float f; unsigned int u; } x; x.f = f;
  unsigned int r = x.u + 0x7fffu + ((x.u >> 16) & 1u);
  return (unsigned short)(r >> 16);
}

static __device__ __forceinline__ void gld_lds16(const void* g, void* l){
  __builtin_amdgcn_global_load_lds(
      (const __attribute__((address_space(1))) void*)g,
      (__attribute__((address_space(3))) void*)l,
      16, 0, 0);
}

// ---------------- elementwise cast x -> bf16 ----------------
__global__ void k_cast(const float* __restrict__ src, unsigned short* __restrict__ dst, int n4){
  int i = blockIdx.x * blockDim.x + threadIdx.x;
  if (i >= n4) return;
  const float4 v = reinterpret_cast<const float4*>(src)[i];
  ushort4 o;
  o.x = f2bf(v.x); o.y = f2bf(v.y); o.z = f2bf(v.z); o.w = f2bf(v.w);
  reinterpret_cast<ushort4*>(dst)[i] = o;
}

// ---------------- transpose + cast 3 weights [in][out] -> [out][in] bf16 ----------
__global__ void k_transpose_cast(const float* __restrict__ Wk, const float* __restrict__ Wv,
                                 const float* __restrict__ Wo,
                                 unsigned short* __restrict__ Tk, unsigned short* __restrict__ Tv,
                                 unsigned short* __restrict__ To){
  __shared__ float tile[64][65];
  const int z = blockIdx.z;
  const float* W = (z == 0) ? Wk : (z == 1) ? Wv : Wo;
  unsigned short* WT = (z == 0) ? Tk : (z == 1) ? Tv : To;
  const int tid = threadIdx.x;
  const int bi = blockIdx.y * 64;
  const int bo = blockIdx.x * 64;
  #pragma unroll
  for (int it = 0; it < 16; ++it){
    int f = it*256 + tid;
    int r = f >> 6, c = f & 63;
    tile[r][c] = W[(size_t)(bi + r) * DIM + bo + c];
  }
  __syncthreads();
  #pragma unroll
  for (int it = 0; it < 16; ++it){
    int f = it*256 + tid;
    int r = f >> 6, c = f & 63;
    WT[(size_t)(bo + r) * DIM + bi + c] = f2bf(tile[c][r]);
  }
}

// ---------------- precompute ewb[h][t][s] = (s<=t) ? bf16(exp(w_aft)) : 0 ----------------
__global__ void k_ew(const float* __restrict__ waft, unsigned short* __restrict__ ewb){
  const int t = blockIdx.x;
  const int h = blockIdx.y;
  const float* src = waft + ((size_t)h*SEQ + t) * SEQ;
  unsigned short* dst = ewb + ((size_t)h*SEQ + t) * SEQ;
  const int smax4 = ((t & ~127) + 128) >> 2;
  for (int i = threadIdx.x; i < smax4; i += blockDim.x){
    const float4 w4 = reinterpret_cast<const float4*>(src)[i];
    const int s = i * 4;
    ushort4 o;
    o.x = (s+0 <= t) ? f2bf(__expf(w4.x)) : (unsigned short)0;
    o.y = (s+1 <= t) ? f2bf(__expf(w4.y)) : (unsigned short)0;
    o.z = (s+2 <= t) ? f2bf(__expf(w4.z)) : (unsigned short)0;
    o.w = (s+3 <= t) ? f2bf(__expf(w4.w)) : (unsigned short)0;
    reinterpret_cast<ushort4*>(dst)[i] = o;
  }
}

// ---------------- fused K/V projection GEMM (BK=32, depth-2 3-buf rotation) ----------------
// L=6 loads/tile (A2,Bk2,Bv2). loads(t+2)->buf[(t+2)%3]; VMCNT(2L)=12 certifies tile t landed.
__global__ __launch_bounds__(256) void k_proj(
    const unsigned short* __restrict__ xb,
    const unsigned short* __restrict__ wkt,
    const unsigned short* __restrict__ wvt,
    const float* __restrict__ bk,
    const float* __restrict__ bv,
    unsigned short* __restrict__ ekb)
{
  __shared__ unsigned short Al[3][128*32];
  __shared__ unsigned short Bkl[3][128*32];
  __shared__ unsigned short Bvl[3][128*32];
  const int tid  = threadIdx.x;
  const int lane = tid & 63;
  const int wr   = tid >> 7;
  const int wc   = (tid >> 6) & 1;
  const int D    = blockIdx.x;
  const int row0 = ((D & 7) * 8 + (D >> 6)) * 128;
  const int col0 = ((D >> 3) & 7) * 128;

  f32x4 acck[4][4] = {};
  f32x4 accv[4][4] = {};

  auto stage = [&](int v, int bi){
    const int kbase = v * 32;
    #pragma unroll
    for (int it = 0; it < 2; ++it){
      const int o = it*4096 + tid*16;
      const int r = o >> 6;
      const int k = (o & 63) >> 1;
      gld_lds16(xb  + (size_t)(row0 + r)*DIM + kbase + k, (char*)&Al[bi][0]  + o);
      gld_lds16(wkt + (size_t)(col0 + r)*DIM + kbase + k, (char*)&Bkl[bi][0] + o);
      gld_lds16(wvt + (size_t)(col0 + r)*DIM + kbase + k, (char*)&Bvl[bi][0] + o);
    }
  };

  stage(0, 0);
  stage(1, 1);

  for (int kt = 0; kt < 32; ++kt){
    if (kt + 2 < 32){
      stage(kt + 2, (kt + 2) % 3);
      VMCNT(12);
    } else if (kt + 2 == 32){
      VMCNT(6);
    } else {
      VMCNT(0);
    }
    SCHED0();
    SBAR();
    SCHED0();
    const int cur = kt % 3;
    const int k0 = (lane >> 4) << 3;
    bf16x8 af[4], bkf[4], bvf[4];
    #pragma unroll
    for (int i = 0; i < 4; ++i)
      af[i] = *reinterpret_cast<const bf16x8*>(&Al[cur][(wr*64 + i*16 + (lane&15))*32 + k0]);
    #pragma unroll
    for (int j = 0; j < 4; ++j){
      bkf[j] = *reinterpret_cast<const bf16x8*>(&Bkl[cur][(wc*64 + j*16 + (lane&15))*32 + k0]);
      bvf[j] = *reinterpret_cast<const bf16x8*>(&Bvl[cur][(wc*64 + j*16 + (lane&15))*32 + k0]);
    }
    #pragma unroll
    for (int i = 0; i < 4; ++i)
      #pragma unroll
      for (int j = 0; j < 4; ++j){
        acck[i][j] = __builtin_amdgcn_mfma_f32_16x16x32_bf16(af[i], bkf[j], acck[i][j], 0, 0, 0);
        accv[i][j] = __builtin_amdgcn_mfma_f32_16x16x32_bf16(af[i], bvf[j], accv[i][j], 0, 0, 0);
      }
    SCHED0();
    SBAR();
    SCHED0();
  }

  #pragma unroll
  for (int j = 0; j < 4; ++j){
    const int c = col0 + wc*64 + j*16 + (lane & 15);
    const int h = c >> 7;
    const int d = c & 127;
    const float bkc = bk[c];
    const float bvc = bv[c];
    #pragma unroll
    for (int i = 0; i < 4; ++i){
      const int r = row0 + wr*64 + i*16 + ((lane>>4)<<2);
      const int n = r >> 11;
      const int s = r & 2047;
      ushort4 pk, pv;
      #pragma unroll
      for (int jj = 0; jj < 4; ++jj){
        const float kval = acck[i][j][jj] + bkc;
        const float vval = accv[i][j][jj] + bvc;
        const float ek  = __expf(kval);
        ((unsigned short*)&pk)[jj] = f2bf(ek);
        ((unsigned short*)&pv)[jj] = f2bf(ek * vval);
      }
      const size_t idx = ((size_t)h*1024 + n*256 + d) * SEQ + s;
      *reinterpret_cast<ushort4*>(&ekb[idx]) = pk;
      *reinterpret_cast<ushort4*>(&ekb[idx + (size_t)128*SEQ]) = pv;
    }
  }
}

// ---------------- AFT causal core: BM=128, BN=256 (interleaved den/num), depth-2 3-buf ----------
// 512 thr = 8 waves (2M x 4N), wave tile 64x64. LDS-B row rr: chunk=rr>>6, sub=rr&63;
// sub<32 -> den col chunk*32+sub, else num col chunk*32+sub-32. Wave wn frags j<2=den, j>=2=num
// at the SAME d -> fused division epilogue. Grid 256: h=D&7, p=(D>>3)>>2, n=(D>>3)&3.
// Triangle pairing {15-p, p}: every block exactly 34 K-steps. L=6 loads/tile, VMCNT(12)/(6)/(0).
__global__ __launch_bounds__(512) void k_core(
    const unsigned short* __restrict__ ewb,
    const unsigned short* __restrict__ ekb,
    unsigned short* __restrict__ aftb)
{
  __shared__ unsigned short Al[3][128*64];   // 48 KB
  __shared__ unsigned short Bl[3][256*64];   // 96 KB
  const int tid  = threadIdx.x;
  const int lane = tid & 63;
  const int wid  = tid >> 6;
  const int wm   = wid >> 2;
  const int wn   = wid & 3;
  const int D  = blockIdx.x;
  const int h  = D & 7;
  const int r_ = D >> 3;
  const int p  = r_ >> 2;
  const int n  = r_ & 3;

  const unsigned short* slab = ekb + ((size_t)h*1024 + n*256) * SEQ;

  #pragma unroll
  for (int half = 0; half < 2; ++half){
    const int tt = half ? p : (15 - p);
    const int t0 = tt * 128;
    const int nst = 2*tt + 2;
    const unsigned short* abase = ewb + ((size_t)h*SEQ + t0) * SEQ;

    f32x4 acc[4][4] = {};

    auto stage = [&](int v, int bi){
      const int s0 = v * 64;
      #pragma unroll
      for (int it = 0; it < 2; ++it){
        const int o = it*8192 + tid*16;
        const int r = o >> 7;
        const int k = (o & 127) >> 1;
        gld_lds16(abase + (size_t)r*SEQ + s0 + k, (char*)&Al[bi][0] + o);
      }
      #pragma unroll
      for (int it = 0; it < 4; ++it){
        const int o = it*8192 + tid*16;
        const int rr = o >> 7;
        const int k = (o & 127) >> 1;
        const int sub = rr & 63;
        const int grow = ((sub >> 5) ? 128 : 0) + (rr >> 6)*32 + (sub & 31);
        gld_lds16(slab + (size_t)grow*SEQ + s0 + k, (char*)&Bl[bi][0] + o);
      }
    };

    stage(0, 0);
    stage(1, 1);

    for (int st = 0; st < nst; ++st){
      if (st + 2 < nst){
        stage(st + 2, (st + 2) % 3);
        VMCNT(12);
      } else if (st + 2 == nst){
        VMCNT(6);
      } else {
        VMCNT(0);
      }
      SCHED0();
      SBAR();
      SCHED0();
      const int cur = st % 3;
      #pragma unroll
      for (int ks = 0; ks < 2; ++ks){
        const int k0 = ks*32 + ((lane >> 4) << 3);
        bf16x8 af[4], bfr[4];
        #pragma unroll
        for (int i = 0; i < 4; ++i)
          af[i] = *reinterpret_cast<const bf16x8*>(&Al[cur][(wm*64 + i*16 + (lane&15))*64 + k0]);
        #pragma unroll
        for (int j = 0; j < 4; ++j)
          bfr[j] = *reinterpret_cast<const bf16x8*>(&Bl[cur][(wn*64 + j*16 + (lane&15))*64 + k0]);
        #pragma unroll
        for (int i = 0; i < 4; ++i)
          #pragma unroll
          for (int j = 0; j < 4; ++j)
            acc[i][j] = __builtin_amdgcn_mfma_f32_16x16x32_bf16(af[i], bfr[j], acc[i][j], 0, 0, 0);
      }
      SCHED0();
      SBAR();
      SCHED0();
    }

    // fused division epilogue: j<2 den, j+2 num at same d
    #pragma unroll
    for (int j = 0; j < 2; ++j){
      const int d = wn*32 + j*16 + (lane & 15);
      #pragma unroll
      for (int i = 0; i < 4; ++i){
        #pragma unroll
        for (int jj = 0; jj < 4; ++jj){
          const int t = t0 + wm*64 + i*16 + ((lane>>4)<<2) + jj;
          aftb[((size_t)n*SEQ + t)*DIM + h*HD + d] = f2bf(acc[i][j+2][jj] / acc[i][j][jj]);
        }
      }
    }
  }
}

// ---------------- output projection GEMM + bias (BK=32, depth-2 3-buf) ----------------
__global__ __launch_bounds__(256) void k_out(
    const unsigned short* __restrict__ aftb,
    const unsigned short* __restrict__ wot,
    const float* __restrict__ bo,
    float* __restrict__ out)
{
  __shared__ unsigned short Al[3][128*32];
  __shared__ unsigned short Bl[3][128*32];
  const int tid  = threadIdx.x;
  const int lane = tid & 63;
  const int wr   = tid >> 7;
  const int wc   = (tid >> 6) & 1;
  const int D    = blockIdx.x;
  const int row0 = ((D & 7) * 8 + (D >> 6)) * 128;
  const int col0 = ((D >> 3) & 7) * 128;

  f32x4 acc[4][4] = {};

  auto stage = [&](int v, int bi){
    const int kbase = v * 32;
    #pragma unroll
    for (int it = 0; it < 2; ++it){
      const int o = it*4096 + tid*16;
      const int r = o >> 6;
      const int k = (o & 63) >> 1;
      gld_lds16(aftb + (size_t)(row0 + r)*DIM + kbase + k, (char*)&Al[bi][0] + o);
      gld_lds16(wot  + (size_t)(col0 + r)*DIM + kbase + k, (char*)&Bl[bi][0] + o);
    }
  };

  stage(0, 0);
  stage(1, 1);

  for (int kt = 0; kt < 32; ++kt){
    if (kt + 2 < 32){
      stage(kt + 2, (kt + 2) % 3);
      VMCNT(8);
    } else if (kt + 2 == 32){
      VMCNT(4);
    } else {
      VMCNT(0);
    }
    SCHED0();
    SBAR();
    SCHED0();
    const int cur = kt % 3;
    const int k0 = (lane >> 4) << 3;
    bf16x8 af[4], bfr[4];
    #pragma unroll
    for (int i = 0; i < 4; ++i)
      af[i] = *reinterpret_cast<const bf16x8*>(&Al[cur][(wr*64 + i*16 + (lane&15))*32 + k0]);
    #pragma unroll
    for (int j = 0; j < 4; ++j)
      bfr[j] = *reinterpret_cast<const bf16x8*>(&Bl[cur][(wc*64 + j*16 + (lane&15))*32 + k0]);
    #pragma unroll
    for (int i = 0; i < 4; ++i)
      #pragma unroll
      for (int j = 0; j < 4; ++j)
        acc[i][j] = __builtin_amdgcn_mfma_f32_16x16x32_bf16(af[i], bfr[j], acc[i][j], 0, 0, 0);
    SCHED0();
    SBAR();
    SCHED0();
  }

  #pragma unroll
  for (int j = 0; j < 4; ++j){
    const int c = col0 + wc*64 + j*16 + (lane & 15);
    const float boc = bo[c];
    #pragma unroll
    for (int i = 0; i < 4; ++i){
      #pragma unroll
      for (int jj = 0; jj < 4; ++jj){
        const int r = row0 + wr*64 + i*16 + ((lane>>4)<<2) + jj;
        out[(size_t)r*DIM + c] = acc[i][j][jj] + boc;
      }
    }
  }
}

extern "C" void kernel_launch(void* const* d_in, const int* in_sizes, int n_in,
                              void* d_out, int out_size, void* d_ws, size_t ws_size,
                              hipStream_t stream){
  const float* x    = (const float*)d_in[0];
  const float* Wk   = (const float*)d_in[1];
  const float* bk   = (const float*)d_in[2];
  const float* Wv   = (const float*)d_in[3];
  const float* bv   = (const float*)d_in[4];
  const float* waft = (const float*)d_in[5];
  const float* Wo   = (const float*)d_in[6];
  const float* bo   = (const float*)d_in[7];
  float* out = (float*)d_out;

  char* w = (char*)d_ws;
  unsigned short* xb   = (unsigned short*)w; w += (size_t)ROWS*DIM*2;       // 16 MB
  unsigned short* wkt  = (unsigned short*)w; w += (size_t)DIM*DIM*2;        // 2 MB
  unsigned short* wvt  = (unsigned short*)w; w += (size_t)DIM*DIM*2;        // 2 MB
  unsigned short* wot  = (unsigned short*)w; w += (size_t)DIM*DIM*2;        // 2 MB
  unsigned short* ekb  = (unsigned short*)w; w += (size_t)HEADS*1024*SEQ*2; // 32 MB
  unsigned short* aftb = (unsigned short*)w; w += (size_t)ROWS*DIM*2;       // 16 MB
  unsigned short* ewb  = (unsigned short*)w; w += (size_t)HEADS*SEQ*SEQ*2;  // 64 MB

  k_cast<<<ROWS*DIM/4/256, 256, 0, stream>>>(x, xb, ROWS*DIM/4);
  k_transpose_cast<<<dim3(16,16,3), 256, 0, stream>>>(Wk, Wv, Wo, wkt, wvt, wot);
  k_ew<<<dim3(SEQ, HEADS), 256, 0, stream>>>(waft, ewb);
  k_proj<<<512, 256, 0, stream>>>(xb, wkt, wvt, bk, bv, ekb);
  k_core<<<256, 512, 0, stream>>>(ewb, ekb, aftb);
  k_out<<<512, 256, 0, stream>>>(aftb, wot, bo, out);
}

// Round 8
// 177.821 us; speedup vs baseline: 1.1415x; 1.1415x over previous
//
#include <hip/hip_runtime.h>
#include <hip/hip_bf16.h>
#include <stdint.h>

#define DIM 1024
#define SEQ 2048
#define NB 4
#define HEADS 8
#define HD 128
#define ROWS (NB*SEQ)   // 8192

typedef __attribute__((ext_vector_type(8))) short bf16x8;
typedef __attribute__((ext_vector_type(4))) float f32x4;

#define VMCNT(n) asm volatile("s_waitcnt vmcnt(" #n ")" ::: "memory")
#define SBAR()   __builtin_amdgcn_s_barrier()
#define SCHED0() __builtin_amdgcn_sched_barrier(0)

static __device__ __forceinline__ unsigned short f2bf(float f){
  union { float f; unsigned int u; } x; x.f = f;
  unsigned int r = x.u + 0x7fffu + ((x.u >> 16) & 1u);
  return (unsigned short)(r >> 16);
}

static __device__ __forceinline__ float bf2f(unsigned short u){
  union { unsigned int u; float f; } x; x.u = ((unsigned int)u) << 16;
  return x.f;
}

static __device__ __forceinline__ void gld_lds16(const void* g, void* l){
  __builtin_amdgcn_global_load_lds(
      (const __attribute__((address_space(1))) void*)g,
      (__attribute__((address_space(3))) void*)l,
      16, 0, 0);
}

// ---------------- elementwise cast x -> bf16 ----------------
__global__ void k_cast(const float* __restrict__ src, unsigned short* __restrict__ dst, int n4){
  int i = blockIdx.x * blockDim.x + threadIdx.x;
  if (i >= n4) return;
  const float4 v = reinterpret_cast<const float4*>(src)[i];
  ushort4 o;
  o.x = f2bf(v.x); o.y = f2bf(v.y); o.z = f2bf(v.z); o.w = f2bf(v.w);
  reinterpret_cast<ushort4*>(dst)[i] = o;
}

// ---------------- transpose + cast 3 weights [in][out] -> [out][in] bf16 ----------
__global__ void k_transpose_cast(const float* __restrict__ Wk, const float* __restrict__ Wv,
                                 const float* __restrict__ Wo,
                                 unsigned short* __restrict__ Tk, unsigned short* __restrict__ Tv,
                                 unsigned short* __restrict__ To){
  __shared__ float tile[64][65];
  const int z = blockIdx.z;
  const float* W = (z == 0) ? Wk : (z == 1) ? Wv : Wo;
  unsigned short* WT = (z == 0) ? Tk : (z == 1) ? Tv : To;
  const int tid = threadIdx.x;
  const int bi = blockIdx.y * 64;
  const int bo = blockIdx.x * 64;
  #pragma unroll
  for (int it = 0; it < 16; ++it){
    int f = it*256 + tid;
    int r = f >> 6, c = f & 63;
    tile[r][c] = W[(size_t)(bi + r) * DIM + bo + c];
  }
  __syncthreads();
  #pragma unroll
  for (int it = 0; it < 16; ++it){
    int f = it*256 + tid;
    int r = f >> 6, c = f & 63;
    WT[(size_t)(bo + r) * DIM + bi + c] = f2bf(tile[c][r]);
  }
}

// ---------------- precompute ewb[h][t][s] = (s<=t) ? bf16(exp(w_aft)) : 0 ----------------
__global__ void k_ew(const float* __restrict__ waft, unsigned short* __restrict__ ewb){
  const int t = blockIdx.x;
  const int h = blockIdx.y;
  const float* src = waft + ((size_t)h*SEQ + t) * SEQ;
  unsigned short* dst = ewb + ((size_t)h*SEQ + t) * SEQ;
  const int smax4 = ((t & ~127) + 128) >> 2;
  for (int i = threadIdx.x; i < smax4; i += blockDim.x){
    const float4 w4 = reinterpret_cast<const float4*>(src)[i];
    const int s = i * 4;
    ushort4 o;
    o.x = (s+0 <= t) ? f2bf(__expf(w4.x)) : (unsigned short)0;
    o.y = (s+1 <= t) ? f2bf(__expf(w4.y)) : (unsigned short)0;
    o.z = (s+2 <= t) ? f2bf(__expf(w4.z)) : (unsigned short)0;
    o.w = (s+3 <= t) ? f2bf(__expf(w4.w)) : (unsigned short)0;
    reinterpret_cast<ushort4*>(dst)[i] = o;
  }
}

// ---------------- fused K/V projection: 8-phase 256^2 schedule ----------------
// Grid 256, 512 threads (8 waves 2Mx4N). Block D: mb=D>>3 (rows mb*256), cb=D&7.
// B-tile rows 0-127 = wkt[cb*128..], rows 128-255 = wvt[cb*128..] (same col range
// for k and v so the exp(k)*v fusion can pair them via an LDS exchange epilogue).
// K-loop: 16 K-tiles of BK=64, 2 LDS slots, 4 phases/tile. Phase q: stage 1 unit
// of tile t+1 (2 gld_lds) | vmcnt(2) at q==0 only | barrier | 12 ds_read_b128 |
// setprio(1) 16 MFMA setprio(0) | barrier.  XOR swizzle k2^=(row&7)<<4 applied on
// BOTH the gld_lds global source and the ds_read address (rule 21).
__global__ __launch_bounds__(512) void k_proj(
    const unsigned short* __restrict__ xb,
    const unsigned short* __restrict__ wkt,
    const unsigned short* __restrict__ wvt,
    const float* __restrict__ bk,
    const float* __restrict__ bv,
    unsigned short* __restrict__ ekb)
{
  __shared__ __align__(16) char smem[131072];   // 2 slots x (A 32KB + B 32KB)
  unsigned short* Asl = (unsigned short*)smem;            // [2][256*64]
  unsigned short* Bsl = (unsigned short*)(smem + 65536);  // [2][256*64]
  float* xch = (float*)smem;                              // epilogue scratch [256][128]

  const int tid  = threadIdx.x;
  const int lane = tid & 63;
  const int lo   = lane & 15;
  const int hi   = lane >> 4;
  const int wid  = tid >> 6;
  const int wm   = wid >> 2;       // 0..1
  const int wn   = wid & 3;        // 0..3
  const int D    = blockIdx.x;
  const int mb   = D >> 3;
  const int cb   = D & 7;
  const int row0 = mb * 256;
  const int col0k = cb * 128;      // k and v column base

  f32x4 acc[8][4] = {};            // [m-frag][n-frag]

  // stage one unit (u: 0=A half0, 1=A half1, 2=B half0(k), 3=B half1(v)) of K-tile kt
  auto stage_unit = [&](int kt, int slot, int u){
    const int half = u & 1;
    const bool isB = (u >> 1) != 0;
    unsigned short* lb = (isB ? Bsl : Asl) + slot*(256*64) + half*(128*64);
    const unsigned short* gb;
    if (!isB)           gb = xb  + (size_t)(row0 + half*128)*DIM + kt*64;
    else if (half == 0) gb = wkt + (size_t)col0k*DIM + kt*64;
    else                gb = wvt + (size_t)col0k*DIM + kt*64;
    #pragma unroll
    for (int it = 0; it < 2; ++it){
      const int po = (it*512 + tid)*16;            // linear LDS dest byte
      const int r  = po >> 7;                      // row within half (0..127)
      const int k2 = (po & 127) ^ ((r & 7) << 4);  // pre-swizzled source byte
      gld_lds16(gb + (size_t)r*DIM + (k2 >> 1), (char*)lb + po);
    }
  };

  // prologue: stage K-tile 0 into slot 0
  #pragma unroll
  for (int u = 0; u < 4; ++u) stage_unit(0, 0, u);

  for (int t = 0; t < 16; ++t){
    const int s = t & 1;
    const char* Ab = (const char*)(Asl + s*(256*64));
    const char* Bb = (const char*)(Bsl + s*(256*64));
    #pragma unroll
    for (int q = 0; q < 4; ++q){
      if (t + 1 < 16) stage_unit(t + 1, s ^ 1, q);
      if (q == 0){
        if (t + 1 < 16) { VMCNT(2); } else { VMCNT(0); }
      }
      SCHED0();
      SBAR();
      SCHED0();
      // ds reads: A quadrant (2 m-frags x 2 kslices) + B all (4 n-frags x 2 kslices)
      bf16x8 a[2][2], b[4][2];
      #pragma unroll
      for (int mf = 0; mf < 2; ++mf){
        const int R = wm*128 + (q*2 + mf)*16 + lo;
        #pragma unroll
        for (int ks = 0; ks < 2; ++ks){
          const int K2 = (ks*64 + hi*16) ^ ((R & 7) << 4);
          a[mf][ks] = *reinterpret_cast<const bf16x8*>(Ab + R*128 + K2);
        }
      }
      #pragma unroll
      for (int nf = 0; nf < 4; ++nf){
        const int R = wn*64 + nf*16 + lo;
        #pragma unroll
        for (int ks = 0; ks < 2; ++ks){
          const int K2 = (ks*64 + hi*16) ^ ((R & 7) << 4);
          b[nf][ks] = *reinterpret_cast<const bf16x8*>(Bb + R*128 + K2);
        }
      }
      __builtin_amdgcn_s_setprio(1);
      #pragma unroll
      for (int ks = 0; ks < 2; ++ks)
        #pragma unroll
        for (int mf = 0; mf < 2; ++mf)
          #pragma unroll
          for (int nf = 0; nf < 4; ++nf)
            acc[q*2+mf][nf] = __builtin_amdgcn_mfma_f32_16x16x32_bf16(
                a[mf][ks], b[nf][ks], acc[q*2+mf][nf], 0, 0, 0);
      __builtin_amdgcn_s_setprio(0);
      SCHED0();
      SBAR();
    }
  }

  // ---- epilogue: v-waves publish acc via LDS; k-waves compute ek, ek*v ----
  __syncthreads();
  if (wn >= 2){
    #pragma unroll
    for (int mf = 0; mf < 8; ++mf){
      const int rloc = wm*128 + mf*16 + hi*4;
      #pragma unroll
      for (int nf = 0; nf < 4; ++nf){
        const int cv = (wn - 2)*64 + nf*16 + lo;   // 0..127
        #pragma unroll
        for (int jj = 0; jj < 4; ++jj)
          xch[(size_t)(rloc + jj)*128 + cv] = acc[mf][nf][jj];
      }
    }
  }
  __syncthreads();
  if (wn < 2){
    #pragma unroll
    for (int nf = 0; nf < 4; ++nf){
      const int ck = wn*64 + nf*16 + lo;           // 0..127
      const int c  = col0k + ck;                   // global k/v col
      const int h  = c >> 7;
      const int d  = c & 127;
      const float bkc = bk[c];
      const float bvc = bv[c];
      #pragma unroll
      for (int mf = 0; mf < 8; ++mf){
        const int rloc = wm*128 + mf*16 + hi*4;
        const int r = row0 + rloc;
        const int n = r >> 11;
        const int sidx = r & 2047;
        ushort4 pk, pv;
        #pragma unroll
        for (int jj = 0; jj < 4; ++jj){
          const float kval = acc[mf][nf][jj] + bkc;
          const float vval = xch[(size_t)(rloc + jj)*128 + ck] + bvc;
          const float ek = __expf(kval);
          ((unsigned short*)&pk)[jj] = f2bf(ek);
          ((unsigned short*)&pv)[jj] = f2bf(ek * vval);
        }
        const size_t idx = ((size_t)h*1024 + n*256 + d) * SEQ + sidx;
        *reinterpret_cast<ushort4*>(&ekb[idx]) = pk;
        *reinterpret_cast<ushort4*>(&ekb[idx + (size_t)128*SEQ]) = pv;
      }
    }
  }
}

// ---------------- AFT causal core (R6: ch-split, triangle-paired, counted-vmcnt dbuf) ----------
__global__ __launch_bounds__(256) void k_core(
    const unsigned short* __restrict__ ewb,
    const unsigned short* __restrict__ ekb,
    unsigned short* __restrict__ dens,
    unsigned short* __restrict__ nums)
{
  __shared__ unsigned short Al[2][128*64];
  __shared__ unsigned short Bl[2][128*64];
  const int tid  = threadIdx.x;
  const int lane = tid & 63;
  const int wr   = tid >> 7;
  const int wc   = (tid >> 6) & 1;
  const int D  = blockIdx.x;
  const int h  = D & 7;
  const int r_ = D >> 3;
  const int p  = r_ >> 3;
  const int n  = (r_ >> 1) & 3;
  const int ch = r_ & 1;

  const unsigned short* bbase = ekb + ((size_t)h*1024 + n*256 + ch*128) * SEQ;
  unsigned short* const outp = ch ? nums : dens;

  #pragma unroll
  for (int half = 0; half < 2; ++half){
    const int tt = half ? p : (15 - p);
    const int t0 = tt * 128;
    const int nst = 2*tt + 2;
    const unsigned short* abase = ewb + ((size_t)h*SEQ + t0) * SEQ;

    f32x4 acc[4][4] = {};

    #pragma unroll
    for (int it = 0; it < 4; ++it){
      const int o = it*4096 + tid*16;
      const int r = o >> 7;
      const int k = (o & 127) >> 1;
      gld_lds16(abase + (size_t)r*SEQ + k, (char*)&Al[0][0] + o);
      gld_lds16(bbase + (size_t)r*SEQ + k, (char*)&Bl[0][0] + o);
    }

    int cur = 0;
    for (int st = 0; st < nst; ++st){
      if (st + 1 < nst){
        const int s0 = (st + 1) * 64;
        #pragma unroll
        for (int it = 0; it < 4; ++it){
          const int o = it*4096 + tid*16;
          const int r = o >> 7;
          const int k = (o & 127) >> 1;
          gld_lds16(abase + (size_t)r*SEQ + s0 + k, (char*)&Al[cur^1][0] + o);
          gld_lds16(bbase + (size_t)r*SEQ + s0 + k, (char*)&Bl[cur^1][0] + o);
        }
        VMCNT(8);
      } else {
        VMCNT(0);
      }
      SCHED0();
      SBAR();
      SCHED0();
      #pragma unroll
      for (int ks = 0; ks < 2; ++ks){
        const int k0 = ks*32 + ((lane >> 4) << 3);
        bf16x8 af[4], bfr[4];
        #pragma unroll
        for (int i = 0; i < 4; ++i)
          af[i] = *reinterpret_cast<const bf16x8*>(&Al[cur][(wr*64 + i*16 + (lane&15))*64 + k0]);
        #pragma unroll
        for (int j = 0; j < 4; ++j)
          bfr[j] = *reinterpret_cast<const bf16x8*>(&Bl[cur][(wc*64 + j*16 + (lane&15))*64 + k0]);
        #pragma unroll
        for (int i = 0; i < 4; ++i)
          #pragma unroll
          for (int j = 0; j < 4; ++j)
            acc[i][j] = __builtin_amdgcn_mfma_f32_16x16x32_bf16(af[i], bfr[j], acc[i][j], 0, 0, 0);
      }
      SCHED0();
      SBAR();
      cur ^= 1;
    }

    #pragma unroll
    for (int j = 0; j < 4; ++j){
      const int d = wc*64 + j*16 + (lane & 15);
      #pragma unroll
      for (int i = 0; i < 4; ++i){
        #pragma unroll
        for (int jj = 0; jj < 4; ++jj){
          const int t = t0 + wr*64 + i*16 + ((lane>>4)<<2) + jj;
          outp[((size_t)n*SEQ + t)*DIM + h*HD + d] = f2bf(acc[i][j][jj]);
        }
      }
    }
    __syncthreads();
  }
}

// ---------------- aft = num/den (bf16 in), cast bf16 ----------------
__global__ void k_div(const unsigned short* __restrict__ nums, const unsigned short* __restrict__ dens,
                      unsigned short* __restrict__ aftb, int n8){
  int i = blockIdx.x * blockDim.x + threadIdx.x;
  if (i >= n8) return;
  ushort4 nu0 = reinterpret_cast<const ushort4*>(nums)[2*i];
  ushort4 nu1 = reinterpret_cast<const ushort4*>(nums)[2*i+1];
  ushort4 de0 = reinterpret_cast<const ushort4*>(dens)[2*i];
  ushort4 de1 = reinterpret_cast<const ushort4*>(dens)[2*i+1];
  ushort4 o0, o1;
  o0.x = f2bf(bf2f(nu0.x)/bf2f(de0.x)); o0.y = f2bf(bf2f(nu0.y)/bf2f(de0.y));
  o0.z = f2bf(bf2f(nu0.z)/bf2f(de0.z)); o0.w = f2bf(bf2f(nu0.w)/bf2f(de0.w));
  o1.x = f2bf(bf2f(nu1.x)/bf2f(de1.x)); o1.y = f2bf(bf2f(nu1.y)/bf2f(de1.y));
  o1.z = f2bf(bf2f(nu1.z)/bf2f(de1.z)); o1.w = f2bf(bf2f(nu1.w)/bf2f(de1.w));
  reinterpret_cast<ushort4*>(aftb)[2*i]   = o0;
  reinterpret_cast<ushort4*>(aftb)[2*i+1] = o1;
}

// ---------------- output projection GEMM + bias (R6: BK=64 counted-vmcnt dbuf) ----------------
__global__ __launch_bounds__(256) void k_out(
    const unsigned short* __restrict__ aftb,
    const unsigned short* __restrict__ wot,
    const float* __restrict__ bo,
    float* __restrict__ out)
{
  __shared__ unsigned short Al[2][128*64];
  __shared__ unsigned short Bl[2][128*64];
  const int tid  = threadIdx.x;
  const int lane = tid & 63;
  const int wr   = tid >> 7;
  const int wc   = (tid >> 6) & 1;
  const int D    = blockIdx.x;
  const int row0 = ((D & 7) * 8 + (D >> 6)) * 128;
  const int col0 = ((D >> 3) & 7) * 128;

  f32x4 acc[4][4] = {};

  #pragma unroll
  for (int it = 0; it < 4; ++it){
    const int o = it*4096 + tid*16;
    const int r = o >> 7;
    const int k = (o & 127) >> 1;
    gld_lds16(aftb + (size_t)(row0 + r)*DIM + k, (char*)&Al[0][0] + o);
    gld_lds16(wot  + (size_t)(col0 + r)*DIM + k, (char*)&Bl[0][0] + o);
  }

  int cur = 0;
  for (int kt = 0; kt < DIM/64; ++kt){
    if (kt + 1 < DIM/64){
      const int kbase = (kt + 1) * 64;
      #pragma unroll
      for (int it = 0; it < 4; ++it){
        const int o = it*4096 + tid*16;
        const int r = o >> 7;
        const int k = (o & 127) >> 1;
        gld_lds16(aftb + (size_t)(row0 + r)*DIM + kbase + k, (char*)&Al[cur^1][0] + o);
        gld_lds16(wot  + (size_t)(col0 + r)*DIM + kbase + k, (char*)&Bl[cur^1][0] + o);
      }
      VMCNT(8);
    } else {
      VMCNT(0);
    }
    SCHED0();
    SBAR();
    SCHED0();
    #pragma unroll
    for (int ks = 0; ks < 2; ++ks){
      const int k0 = ks*32 + ((lane >> 4) << 3);
      bf16x8 af[4], bfr[4];
      #pragma unroll
      for (int i = 0; i < 4; ++i)
        af[i] = *reinterpret_cast<const bf16x8*>(&Al[cur][(wr*64 + i*16 + (lane&15))*64 + k0]);
      #pragma unroll
      for (int j = 0; j < 4; ++j)
        bfr[j] = *reinterpret_cast<const bf16x8*>(&Bl[cur][(wc*64 + j*16 + (lane&15))*64 + k0]);
      #pragma unroll
      for (int i = 0; i < 4; ++i)
        #pragma unroll
        for (int j = 0; j < 4; ++j)
          acc[i][j] = __builtin_amdgcn_mfma_f32_16x16x32_bf16(af[i], bfr[j], acc[i][j], 0, 0, 0);
    }
    SCHED0();
    SBAR();
    cur ^= 1;
  }

  #pragma unroll
  for (int j = 0; j < 4; ++j){
    const int c = col0 + wc*64 + j*16 + (lane & 15);
    const float boc = bo[c];
    #pragma unroll
    for (int i = 0; i < 4; ++i){
      #pragma unroll
      for (int jj = 0; jj < 4; ++jj){
        const int r = row0 + wr*64 + i*16 + ((lane>>4)<<2) + jj;
        out[(size_t)r*DIM + c] = acc[i][j][jj] + boc;
      }
    }
  }
}

extern "C" void kernel_launch(void* const* d_in, const int* in_sizes, int n_in,
                              void* d_out, int out_size, void* d_ws, size_t ws_size,
                              hipStream_t stream){
  const float* x    = (const float*)d_in[0];
  const float* Wk   = (const float*)d_in[1];
  const float* bk   = (const float*)d_in[2];
  const float* Wv   = (const float*)d_in[3];
  const float* bv   = (const float*)d_in[4];
  const float* waft = (const float*)d_in[5];
  const float* Wo   = (const float*)d_in[6];
  const float* bo   = (const float*)d_in[7];
  float* out = (float*)d_out;

  char* w = (char*)d_ws;
  unsigned short* xb   = (unsigned short*)w; w += (size_t)ROWS*DIM*2;       // 16 MB
  unsigned short* wkt  = (unsigned short*)w; w += (size_t)DIM*DIM*2;        // 2 MB
  unsigned short* wvt  = (unsigned short*)w; w += (size_t)DIM*DIM*2;        // 2 MB
  unsigned short* wot  = (unsigned short*)w; w += (size_t)DIM*DIM*2;        // 2 MB
  unsigned short* ekb  = (unsigned short*)w; w += (size_t)HEADS*1024*SEQ*2; // 32 MB
  unsigned short* dens = (unsigned short*)w; w += (size_t)ROWS*DIM*2;       // 16 MB
  unsigned short* nums = (unsigned short*)w; w += (size_t)ROWS*DIM*2;       // 16 MB
  unsigned short* aftb = (unsigned short*)w; w += (size_t)ROWS*DIM*2;       // 16 MB
  unsigned short* ewb  = (unsigned short*)w; w += (size_t)HEADS*SEQ*SEQ*2;  // 64 MB

  k_cast<<<ROWS*DIM/4/256, 256, 0, stream>>>(x, xb, ROWS*DIM/4);
  k_transpose_cast<<<dim3(16,16,3), 256, 0, stream>>>(Wk, Wv, Wo, wkt, wvt, wot);
  k_ew<<<dim3(SEQ, HEADS), 256, 0, stream>>>(waft, ewb);
  k_proj<<<256, 512, 0, stream>>>(xb, wkt, wvt, bk, bv, ekb);
  k_core<<<512, 256, 0, stream>>>(ewb, ekb, dens, nums);
  k_div<<<ROWS*DIM/8/256, 256, 0, stream>>>(nums, dens, aftb, ROWS*DIM/8);
  k_out<<<512, 256, 0, stream>>>(aftb, wot, bo, out);
}

// Round 9
// 164.829 us; speedup vs baseline: 1.2315x; 1.0788x over previous
//
#include <hip/hip_runtime.h>
#include <hip/hip_bf16.h>
#include <stdint.h>

#define DIM 1024
#define SEQ 2048
#define NB 4
#define HEADS 8
#define HD 128
#define ROWS (NB*SEQ)   // 8192

typedef __attribute__((ext_vector_type(8))) short bf16x8;
typedef __attribute__((ext_vector_type(4))) float f32x4;

#define VMCNT(n) asm volatile("s_waitcnt vmcnt(" #n ")" ::: "memory")
#define SBAR()   __builtin_amdgcn_s_barrier()
#define SCHED0() __builtin_amdgcn_sched_barrier(0)

static __device__ __forceinline__ unsigned short f2bf(float f){
  union { float f; unsigned int u; } x; x.f = f;
  unsigned int r = x.u + 0x7fffu + ((x.u >> 16) & 1u);
  return (unsigned short)(r >> 16);
}

static __device__ __forceinline__ void gld_lds16(const void* g, void* l){
  __builtin_amdgcn_global_load_lds(
      (const __attribute__((address_space(1))) void*)g,
      (__attribute__((address_space(3))) void*)l,
      16, 0, 0);
}

// ---------------- elementwise cast x -> bf16 ----------------
__global__ void k_cast(const float* __restrict__ src, unsigned short* __restrict__ dst, int n4){
  int i = blockIdx.x * blockDim.x + threadIdx.x;
  if (i >= n4) return;
  const float4 v = reinterpret_cast<const float4*>(src)[i];
  ushort4 o;
  o.x = f2bf(v.x); o.y = f2bf(v.y); o.z = f2bf(v.z); o.w = f2bf(v.w);
  reinterpret_cast<ushort4*>(dst)[i] = o;
}

// ---------------- transpose + cast 3 weights [in][out] -> [out][in] bf16 ----------
__global__ void k_transpose_cast(const float* __restrict__ Wk, const float* __restrict__ Wv,
                                 const float* __restrict__ Wo,
                                 unsigned short* __restrict__ Tk, unsigned short* __restrict__ Tv,
                                 unsigned short* __restrict__ To){
  __shared__ float tile[64][65];
  const int z = blockIdx.z;
  const float* W = (z == 0) ? Wk : (z == 1) ? Wv : Wo;
  unsigned short* WT = (z == 0) ? Tk : (z == 1) ? Tv : To;
  const int tid = threadIdx.x;
  const int bi = blockIdx.y * 64;
  const int bo = blockIdx.x * 64;
  #pragma unroll
  for (int it = 0; it < 16; ++it){
    int f = it*256 + tid;
    int r = f >> 6, c = f & 63;
    tile[r][c] = W[(size_t)(bi + r) * DIM + bo + c];
  }
  __syncthreads();
  #pragma unroll
  for (int it = 0; it < 16; ++it){
    int f = it*256 + tid;
    int r = f >> 6, c = f & 63;
    WT[(size_t)(bo + r) * DIM + bi + c] = f2bf(tile[c][r]);
  }
}

// ---------------- precompute ewb[h][t][s] = (s<=t) ? bf16(exp(w_aft)) : 0 ----------------
__global__ void k_ew(const float* __restrict__ waft, unsigned short* __restrict__ ewb){
  const int t = blockIdx.x;
  const int h = blockIdx.y;
  const float* src = waft + ((size_t)h*SEQ + t) * SEQ;
  unsigned short* dst = ewb + ((size_t)h*SEQ + t) * SEQ;
  const int smax4 = ((t & ~127) + 128) >> 2;
  for (int i = threadIdx.x; i < smax4; i += blockDim.x){
    const float4 w4 = reinterpret_cast<const float4*>(src)[i];
    const int s = i * 4;
    ushort4 o;
    o.x = (s+0 <= t) ? f2bf(__expf(w4.x)) : (unsigned short)0;
    o.y = (s+1 <= t) ? f2bf(__expf(w4.y)) : (unsigned short)0;
    o.z = (s+2 <= t) ? f2bf(__expf(w4.z)) : (unsigned short)0;
    o.w = (s+3 <= t) ? f2bf(__expf(w4.w)) : (unsigned short)0;
    reinterpret_cast<ushort4*>(dst)[i] = o;
  }
}

// ---------------- fused K/V projection: 8-phase 256^2 schedule (R8, proven) ----------------
__global__ __launch_bounds__(512) void k_proj(
    const unsigned short* __restrict__ xb,
    const unsigned short* __restrict__ wkt,
    const unsigned short* __restrict__ wvt,
    const float* __restrict__ bk,
    const float* __restrict__ bv,
    unsigned short* __restrict__ ekb)
{
  __shared__ __align__(16) char smem[131072];
  unsigned short* Asl = (unsigned short*)smem;            // [2][256*64]
  unsigned short* Bsl = (unsigned short*)(smem + 65536);  // [2][256*64]
  float* xch = (float*)smem;                              // epilogue scratch [256][128]

  const int tid  = threadIdx.x;
  const int lane = tid & 63;
  const int lo   = lane & 15;
  const int hi   = lane >> 4;
  const int wid  = tid >> 6;
  const int wm   = wid >> 2;
  const int wn   = wid & 3;
  const int D    = blockIdx.x;
  const int mb   = D >> 3;
  const int cb   = D & 7;
  const int row0 = mb * 256;
  const int col0k = cb * 128;

  f32x4 acc[8][4] = {};

  auto stage_unit = [&](int kt, int slot, int u){
    const int half = u & 1;
    const bool isB = (u >> 1) != 0;
    unsigned short* lb = (isB ? Bsl : Asl) + slot*(256*64) + half*(128*64);
    const unsigned short* gb;
    if (!isB)           gb = xb  + (size_t)(row0 + half*128)*DIM + kt*64;
    else if (half == 0) gb = wkt + (size_t)col0k*DIM + kt*64;
    else                gb = wvt + (size_t)col0k*DIM + kt*64;
    #pragma unroll
    for (int it = 0; it < 2; ++it){
      const int po = (it*512 + tid)*16;
      const int r  = po >> 7;
      const int k2 = (po & 127) ^ ((r & 7) << 4);
      gld_lds16(gb + (size_t)r*DIM + (k2 >> 1), (char*)lb + po);
    }
  };

  #pragma unroll
  for (int u = 0; u < 4; ++u) stage_unit(0, 0, u);

  for (int t = 0; t < 16; ++t){
    const int s = t & 1;
    const char* Ab = (const char*)(Asl + s*(256*64));
    const char* Bb = (const char*)(Bsl + s*(256*64));
    #pragma unroll
    for (int q = 0; q < 4; ++q){
      if (t + 1 < 16) stage_unit(t + 1, s ^ 1, q);
      if (q == 0){
        if (t + 1 < 16) { VMCNT(2); } else { VMCNT(0); }
      }
      SCHED0();
      SBAR();
      SCHED0();
      bf16x8 a[2][2], b[4][2];
      #pragma unroll
      for (int mf = 0; mf < 2; ++mf){
        const int R = wm*128 + (q*2 + mf)*16 + lo;
        #pragma unroll
        for (int ks = 0; ks < 2; ++ks){
          const int K2 = (ks*64 + hi*16) ^ ((R & 7) << 4);
          a[mf][ks] = *reinterpret_cast<const bf16x8*>(Ab + R*128 + K2);
        }
      }
      #pragma unroll
      for (int nf = 0; nf < 4; ++nf){
        const int R = wn*64 + nf*16 + lo;
        #pragma unroll
        for (int ks = 0; ks < 2; ++ks){
          const int K2 = (ks*64 + hi*16) ^ ((R & 7) << 4);
          b[nf][ks] = *reinterpret_cast<const bf16x8*>(Bb + R*128 + K2);
        }
      }
      __builtin_amdgcn_s_setprio(1);
      #pragma unroll
      for (int ks = 0; ks < 2; ++ks)
        #pragma unroll
        for (int mf = 0; mf < 2; ++mf)
          #pragma unroll
          for (int nf = 0; nf < 4; ++nf)
            acc[q*2+mf][nf] = __builtin_amdgcn_mfma_f32_16x16x32_bf16(
                a[mf][ks], b[nf][ks], acc[q*2+mf][nf], 0, 0, 0);
      __builtin_amdgcn_s_setprio(0);
      SCHED0();
      SBAR();
    }
  }

  __syncthreads();
  if (wn >= 2){
    #pragma unroll
    for (int mf = 0; mf < 8; ++mf){
      const int rloc = wm*128 + mf*16 + hi*4;
      #pragma unroll
      for (int nf = 0; nf < 4; ++nf){
        const int cv = (wn - 2)*64 + nf*16 + lo;
        #pragma unroll
        for (int jj = 0; jj < 4; ++jj)
          xch[(size_t)(rloc + jj)*128 + cv] = acc[mf][nf][jj];
      }
    }
  }
  __syncthreads();
  if (wn < 2){
    #pragma unroll
    for (int nf = 0; nf < 4; ++nf){
      const int ck = wn*64 + nf*16 + lo;
      const int c  = col0k + ck;
      const int h  = c >> 7;
      const int d  = c & 127;
      const float bkc = bk[c];
      const float bvc = bv[c];
      #pragma unroll
      for (int mf = 0; mf < 8; ++mf){
        const int rloc = wm*128 + mf*16 + hi*4;
        const int r = row0 + rloc;
        const int n = r >> 11;
        const int sidx = r & 2047;
        ushort4 pk, pv;
        #pragma unroll
        for (int jj = 0; jj < 4; ++jj){
          const float kval = acc[mf][nf][jj] + bkc;
          const float vval = xch[(size_t)(rloc + jj)*128 + ck] + bvc;
          const float ek = __expf(kval);
          ((unsigned short*)&pk)[jj] = f2bf(ek);
          ((unsigned short*)&pv)[jj] = f2bf(ek * vval);
        }
        const size_t idx = ((size_t)h*1024 + n*256 + d) * SEQ + sidx;
        *reinterpret_cast<ushort4*>(&ekb[idx]) = pk;
        *reinterpret_cast<ushort4*>(&ekb[idx + (size_t)128*SEQ]) = pv;
      }
    }
  }
}

// ---------------- AFT causal core: 8-phase, BM=128 BN=256 (den|num), fused division ----------
// Grid 256, 512 thr (8 waves 2Mx4N, wave tile 64x64). h=D&7, r_=D>>3, p=r_>>2, n=r_&3.
// Triangle pair {15-p, p}: 34 K-steps/block. B rows 0-127 = ek (den), 128-255 = ekv (num).
// Epilogue: num waves (wn>=2) publish via padded LDS; den waves write aftb = num/den.
__global__ __launch_bounds__(512) void k_core(
    const unsigned short* __restrict__ ewb,
    const unsigned short* __restrict__ ekb,
    unsigned short* __restrict__ aftb)
{
  __shared__ __align__(16) char smem[98304];              // A[2][128*64] + B[2][256*64]
  unsigned short* Asl = (unsigned short*)smem;            // 32 KB
  unsigned short* Bsl = (unsigned short*)(smem + 32768);  // 64 KB
  float* xch = (float*)smem;                              // epilogue [128][129] f32 = 66 KB

  const int tid  = threadIdx.x;
  const int lane = tid & 63;
  const int lo   = lane & 15;
  const int hi   = lane >> 4;
  const int wid  = tid >> 6;
  const int wm   = wid >> 2;       // 0..1
  const int wn   = wid & 3;        // 0..3
  const int D  = blockIdx.x;
  const int h  = D & 7;
  const int r_ = D >> 3;
  const int p  = r_ >> 2;
  const int n  = r_ & 3;

  const unsigned short* slab = ekb + ((size_t)h*1024 + n*256) * SEQ;

  #pragma unroll
  for (int half = 0; half < 2; ++half){
    const int tt = half ? p : (15 - p);
    const int t0 = tt * 128;
    const int nst = 2*tt + 2;
    const unsigned short* abase = ewb + ((size_t)h*SEQ + t0) * SEQ;

    f32x4 acc[4][4] = {};

    // unit u: u<2 -> A rows u*64.., u>=2 -> B rows (u-2)*64.. ; 1 gld/thread (8KB)
    auto stage_unit = [&](int st, int slot, int u){
      const int s0 = st * 64;
      const int po = tid * 16;
      const int r  = po >> 7;                      // 0..63 within unit
      const int k2 = (po & 127) ^ ((r & 7) << 4);
      if (u < 2){
        unsigned short* lb = Asl + slot*(128*64) + u*(64*64);
        gld_lds16(abase + (size_t)(u*64 + r)*SEQ + s0 + (k2 >> 1), (char*)lb + po);
      } else {
        unsigned short* lb = Bsl + slot*(256*64) + (u-2)*(64*64);
        gld_lds16(slab + (size_t)((u-2)*64 + r)*SEQ + s0 + (k2 >> 1), (char*)lb + po);
      }
    };

    #pragma unroll
    for (int u = 0; u < 6; ++u) stage_unit(0, 0, u);

    for (int t = 0; t < nst; ++t){
      const int s = t & 1;
      const char* Ab = (const char*)(Asl + s*(128*64));
      const char* Bb = (const char*)(Bsl + s*(256*64));
      #pragma unroll
      for (int q = 0; q < 4; ++q){
        if (q < 3 && t + 1 < nst){
          stage_unit(t + 1, s ^ 1, q*2);
          stage_unit(t + 1, s ^ 1, q*2 + 1);
        }
        if (q == 0){
          if (t + 1 < nst) { VMCNT(2); } else { VMCNT(0); }
        }
        SCHED0();
        SBAR();
        SCHED0();
        bf16x8 a[2], b[4][2];
        {
          const int R = wm*64 + q*16 + lo;
          #pragma unroll
          for (int ks = 0; ks < 2; ++ks){
            const int K2 = (ks*64 + hi*16) ^ ((R & 7) << 4);
            a[ks] = *reinterpret_cast<const bf16x8*>(Ab + R*128 + K2);
          }
        }
        #pragma unroll
        for (int nf = 0; nf < 4; ++nf){
          const int R = wn*64 + nf*16 + lo;
          #pragma unroll
          for (int ks = 0; ks < 2; ++ks){
            const int K2 = (ks*64 + hi*16) ^ ((R & 7) << 4);
            b[nf][ks] = *reinterpret_cast<const bf16x8*>(Bb + R*128 + K2);
          }
        }
        __builtin_amdgcn_s_setprio(1);
        #pragma unroll
        for (int ks = 0; ks < 2; ++ks)
          #pragma unroll
          for (int nf = 0; nf < 4; ++nf)
            acc[q][nf] = __builtin_amdgcn_mfma_f32_16x16x32_bf16(
                a[ks], b[nf][ks], acc[q][nf], 0, 0, 0);
        __builtin_amdgcn_s_setprio(0);
        SCHED0();
        SBAR();
      }
    }

    // ---- fused division epilogue ----
    __syncthreads();
    if (wn >= 2){
      #pragma unroll
      for (int mf = 0; mf < 4; ++mf){
        const int rloc = wm*64 + mf*16 + hi*4;
        #pragma unroll
        for (int nf = 0; nf < 4; ++nf){
          const int dv = (wn - 2)*64 + nf*16 + lo;     // num col 0..127
          #pragma unroll
          for (int jj = 0; jj < 4; ++jj)
            xch[(size_t)(rloc + jj)*129 + dv] = acc[mf][nf][jj];
        }
      }
    }
    __syncthreads();
    if (wn < 2){
      #pragma unroll
      for (int nf = 0; nf < 4; ++nf){
        const int d = wn*64 + nf*16 + lo;              // den col 0..127
        #pragma unroll
        for (int mf = 0; mf < 4; ++mf){
          const int rloc = wm*64 + mf*16 + hi*4;
          #pragma unroll
          for (int jj = 0; jj < 4; ++jj){
            const int t = t0 + rloc + jj;
            const float num = xch[(size_t)(rloc + jj)*129 + d];
            aftb[((size_t)n*SEQ + t)*DIM + h*HD + d] = f2bf(num / acc[mf][nf][jj]);
          }
        }
      }
    }
    __syncthreads();   // xch reads done before next half's staging reuses smem
  }
}

// ---------------- output projection: 8-phase, BM=128 BN=256 ----------------
// Grid 256: rb=D>>2 (rows rb*128), cb=D&3 (cols cb*256). 512 thr, wave tile 64x64.
__global__ __launch_bounds__(512) void k_out(
    const unsigned short* __restrict__ aftb,
    const unsigned short* __restrict__ wot,
    const float* __restrict__ bo,
    float* __restrict__ out)
{
  __shared__ __align__(16) char smem[98304];
  unsigned short* Asl = (unsigned short*)smem;            // [2][128*64]
  unsigned short* Bsl = (unsigned short*)(smem + 32768);  // [2][256*64]

  const int tid  = threadIdx.x;
  const int lane = tid & 63;
  const int lo   = lane & 15;
  const int hi   = lane >> 4;
  const int wid  = tid >> 6;
  const int wm   = wid >> 2;
  const int wn   = wid & 3;
  const int D    = blockIdx.x;
  const int row0 = (D >> 2) * 128;
  const int col0 = (D & 3) * 256;

  f32x4 acc[4][4] = {};

  auto stage_unit = [&](int kt, int slot, int u){
    const int po = tid * 16;
    const int r  = po >> 7;
    const int k2 = (po & 127) ^ ((r & 7) << 4);
    if (u < 2){
      unsigned short* lb = Asl + slot*(128*64) + u*(64*64);
      gld_lds16(aftb + (size_t)(row0 + u*64 + r)*DIM + kt*64 + (k2 >> 1), (char*)lb + po);
    } else {
      unsigned short* lb = Bsl + slot*(256*64) + (u-2)*(64*64);
      gld_lds16(wot + (size_t)(col0 + (u-2)*64 + r)*DIM + kt*64 + (k2 >> 1), (char*)lb + po);
    }
  };

  #pragma unroll
  for (int u = 0; u < 6; ++u) stage_unit(0, 0, u);

  for (int t = 0; t < 16; ++t){
    const int s = t & 1;
    const char* Ab = (const char*)(Asl + s*(128*64));
    const char* Bb = (const char*)(Bsl + s*(256*64));
    #pragma unroll
    for (int q = 0; q < 4; ++q){
      if (q < 3 && t + 1 < 16){
        stage_unit(t + 1, s ^ 1, q*2);
        stage_unit(t + 1, s ^ 1, q*2 + 1);
      }
      if (q == 0){
        if (t + 1 < 16) { VMCNT(2); } else { VMCNT(0); }
      }
      SCHED0();
      SBAR();
      SCHED0();
      bf16x8 a[2], b[4][2];
      {
        const int R = wm*64 + q*16 + lo;
        #pragma unroll
        for (int ks = 0; ks < 2; ++ks){
          const int K2 = (ks*64 + hi*16) ^ ((R & 7) << 4);
          a[ks] = *reinterpret_cast<const bf16x8*>(Ab + R*128 + K2);
        }
      }
      #pragma unroll
      for (int nf = 0; nf < 4; ++nf){
        const int R = wn*64 + nf*16 + lo;
        #pragma unroll
        for (int ks = 0; ks < 2; ++ks){
          const int K2 = (ks*64 + hi*16) ^ ((R & 7) << 4);
          b[nf][ks] = *reinterpret_cast<const bf16x8*>(Bb + R*128 + K2);
        }
      }
      __builtin_amdgcn_s_setprio(1);
      #pragma unroll
      for (int ks = 0; ks < 2; ++ks)
        #pragma unroll
        for (int nf = 0; nf < 4; ++nf)
          acc[q][nf] = __builtin_amdgcn_mfma_f32_16x16x32_bf16(
              a[ks], b[nf][ks], acc[q][nf], 0, 0, 0);
      __builtin_amdgcn_s_setprio(0);
      SCHED0();
      SBAR();
    }
  }

  #pragma unroll
  for (int nf = 0; nf < 4; ++nf){
    const int c = col0 + wn*64 + nf*16 + lo;
    const float boc = bo[c];
    #pragma unroll
    for (int mf = 0; mf < 4; ++mf){
      #pragma unroll
      for (int jj = 0; jj < 4; ++jj){
        const int r = row0 + wm*64 + mf*16 + hi*4 + jj;
        out[(size_t)r*DIM + c] = acc[mf][nf][jj] + boc;
      }
    }
  }
}

extern "C" void kernel_launch(void* const* d_in, const int* in_sizes, int n_in,
                              void* d_out, int out_size, void* d_ws, size_t ws_size,
                              hipStream_t stream){
  const float* x    = (const float*)d_in[0];
  const float* Wk   = (const float*)d_in[1];
  const float* bk   = (const float*)d_in[2];
  const float* Wv   = (const float*)d_in[3];
  const float* bv   = (const float*)d_in[4];
  const float* waft = (const float*)d_in[5];
  const float* Wo   = (const float*)d_in[6];
  const float* bo   = (const float*)d_in[7];
  float* out = (float*)d_out;

  char* w = (char*)d_ws;
  unsigned short* xb   = (unsigned short*)w; w += (size_t)ROWS*DIM*2;       // 16 MB
  unsigned short* wkt  = (unsigned short*)w; w += (size_t)DIM*DIM*2;        // 2 MB
  unsigned short* wvt  = (unsigned short*)w; w += (size_t)DIM*DIM*2;        // 2 MB
  unsigned short* wot  = (unsigned short*)w; w += (size_t)DIM*DIM*2;        // 2 MB
  unsigned short* ekb  = (unsigned short*)w; w += (size_t)HEADS*1024*SEQ*2; // 32 MB
  unsigned short* aftb = (unsigned short*)w; w += (size_t)ROWS*DIM*2;       // 16 MB
  unsigned short* ewb  = (unsigned short*)w; w += (size_t)HEADS*SEQ*SEQ*2;  // 64 MB

  k_cast<<<ROWS*DIM/4/256, 256, 0, stream>>>(x, xb, ROWS*DIM/4);
  k_transpose_cast<<<dim3(16,16,3), 256, 0, stream>>>(Wk, Wv, Wo, wkt, wvt, wot);
  k_ew<<<dim3(SEQ, HEADS), 256, 0, stream>>>(waft, ewb);
  k_proj<<<256, 512, 0, stream>>>(xb, wkt, wvt, bk, bv, ekb);
  k_core<<<256, 512, 0, stream>>>(ewb, ekb, aftb);
  k_out<<<256, 512, 0, stream>>>(aftb, wot, bo, out);
}